// Round 11
// baseline (13868.059 us; speedup 1.0000x reference)
//
#include <hip/hip_runtime.h>

// ---------------------------------------------------------------------------
// TransitionDown: FPS (M=N/4) -> KNN(K=16) -> Linear(64->128)+ReLU -> max-pool
// Round 15: r11 (measured-best, 1.43us/step) + the M1-overlap restructure.
// Measured lesson from r13/r14: the step's currency is ALL-THREAD issue in
// barrier-gated intervals; L2 loads are hidden. So move the global-argmax
// work off the all-thread path:
//   - Exact decomposition: new global max = max(M1, U), where
//     M1 = fold over chunks NOT updated this step (their ckey is stable
//          during phase 2 -> computed in the A->B interval by the ~448
//          threads idle there; hidden under phase-2 latency),
//     U  = fold over the na updated chunks (wave 0 only, B->C interval;
//          waves 1-7 arrive at barrier C instantly).
//     Keys unique (orig embedded) => max(M1,U) == full fold, bit-exact.
//   - Active/inactive = each thread's own phase-1 predicate (register flag):
//     no extra reads; M1 reads only inactive ckey, phase 2 writes only
//     active ckey -> no races.
// Everything else byte-identical to r11 (passed 2x): dynamic alist, 8-thr/
// chunk update (3x float4 + uint4, mind b128 rmw + XOR bit[2:5] swizzle),
// skip rule dlb*0.99999>=cmax (fmin identity => bit-exact), key
// (mbits<<32)|~orig, plain dppmax64 ladder, global pick-coord loads.
// ---------------------------------------------------------------------------

#define FPS_T   512
#define NC      512
#define KNN_K   16
#define MLP_ROWS 32

#define DPPU(X, CTRL) ((unsigned)__builtin_amdgcn_update_dpp(                 \
    (int)(X), (int)(X), (CTRL), 0xf, 0xf, false))

// 64-bit max-combine with DPP-shifted partner (r8/r11-validated).
__device__ __forceinline__ unsigned long long dppmax64(unsigned long long k,
                                                       const int ctrl)
{
    const unsigned lo = (unsigned)k, hi = (unsigned)(k >> 32);
    unsigned nlo, nhi;
    switch (ctrl) {   // ctrl must be a literal constant per call site
    case 0xB1:  nlo = DPPU(lo, 0xB1);  nhi = DPPU(hi, 0xB1);  break;
    case 0x4E:  nlo = DPPU(lo, 0x4E);  nhi = DPPU(hi, 0x4E);  break;
    case 0x141: nlo = DPPU(lo, 0x141); nhi = DPPU(hi, 0x141); break;
    case 0x140: nlo = DPPU(lo, 0x140); nhi = DPPU(hi, 0x140); break;
    case 0x142: nlo = DPPU(lo, 0x142); nhi = DPPU(hi, 0x142); break;
    default:    nlo = DPPU(lo, 0x143); nhi = DPPU(hi, 0x143); break;
    }
    const unsigned long long nk = ((unsigned long long)nhi << 32) | nlo;
    return nk > k ? nk : k;
}

// --- SoA transpose of pos for coalesced per-coordinate access ---------------
__global__ void prep_kernel(const float* __restrict__ pos, float* __restrict__ posx,
                            float* __restrict__ posy, float* __restrict__ posz, int N)
{
    const int i = blockIdx.x * blockDim.x + threadIdx.x;
    if (i < N) {
        posx[i] = pos[3 * i + 0];
        posy[i] = pos[3 * i + 1];
        posz[i] = pos[3 * i + 2];
    }
}

// --- Morton-bucket counting sort (spatial permutation; orig idx carried) ----
__device__ __forceinline__ unsigned spread4(unsigned x)
{
    return (x & 1u) | ((x & 2u) << 2) | ((x & 4u) << 4) | ((x & 8u) << 6);
}
__device__ __forceinline__ unsigned mcode(float x, float y, float z)
{
    int qx = (int)((x + 6.0f) * (16.0f / 12.0f));
    int qy = (int)((y + 6.0f) * (16.0f / 12.0f));
    int qz = (int)((z + 6.0f) * (16.0f / 12.0f));
    qx = qx < 0 ? 0 : (qx > 15 ? 15 : qx);
    qy = qy < 0 ? 0 : (qy > 15 ? 15 : qy);
    qz = qz < 0 ? 0 : (qz > 15 ? 15 : qz);
    return spread4((unsigned)qx) | (spread4((unsigned)qy) << 1)
         | (spread4((unsigned)qz) << 2);
}

__global__ __launch_bounds__(1024) void sort_kernel(
    const float* __restrict__ posx, const float* __restrict__ posy,
    const float* __restrict__ posz, float* __restrict__ xs,
    float* __restrict__ ys, float* __restrict__ zs,
    unsigned* __restrict__ orig, int N)
{
    __shared__ unsigned cnt[4096];
    __shared__ unsigned base[4096];
    const int t = threadIdx.x;

    for (int i = t; i < 4096; i += 1024) cnt[i] = 0;
    __syncthreads();
    for (int i = t; i < N; i += 1024)
        atomicAdd(&cnt[mcode(posx[i], posy[i], posz[i])], 1u);
    __syncthreads();
    if (t == 0) {
        unsigned run = 0;
        for (int c = 0; c < 4096; ++c) { base[c] = run; run += cnt[c]; }
    }
    __syncthreads();
    for (int i = t; i < 4096; i += 1024) cnt[i] = 0;
    __syncthreads();
    for (int i = t; i < N; i += 1024) {
        const float px = posx[i], py = posy[i], pz = posz[i];
        const unsigned m = mcode(px, py, pz);
        const unsigned d = base[m] + atomicAdd(&cnt[m], 1u);
        xs[d] = px; ys[d] = py; zs[d] = pz; orig[d] = (unsigned)i;
    }
}

// --- per-chunk bbox (exact fmin/fmax of member coords) ----------------------
__global__ __launch_bounds__(64) void bbox_kernel(
    const float* __restrict__ xs, const float* __restrict__ ys,
    const float* __restrict__ zs, float* __restrict__ bboxG)
{
    const int c = blockIdx.x, l = threadIdx.x;
    const int i = c * 64 + l;
    float xmn = xs[i], xmx = xmn;
    float ymn = ys[i], ymx = ymn;
    float zmn = zs[i], zmx = zmn;
#pragma unroll
    for (int off = 32; off > 0; off >>= 1) {
        xmn = fminf(xmn, __shfl_xor(xmn, off));
        xmx = fmaxf(xmx, __shfl_xor(xmx, off));
        ymn = fminf(ymn, __shfl_xor(ymn, off));
        ymx = fmaxf(ymx, __shfl_xor(ymx, off));
        zmn = fminf(zmn, __shfl_xor(zmn, off));
        zmx = fmaxf(zmx, __shfl_xor(zmx, off));
    }
    if (l == 0) {
        float* o = &bboxG[c * 6];
        o[0] = xmn; o[1] = xmx; o[2] = ymn; o[3] = ymx; o[4] = zmn; o[5] = zmx;
    }
}

// --- h = relu(x @ W + b), x[N,64], W[64,128], h[N,128] ----------------------
__global__ __launch_bounds__(256) void mlp_kernel(
    const float* __restrict__ x, const float* __restrict__ W,
    const float* __restrict__ b, float* __restrict__ h, int N)
{
    __shared__ float ws[64 * 128];
    __shared__ float xs[MLP_ROWS * 65];   // +1 pad: breaks 8-way bank conflict
    const int t = threadIdx.x;
    const int r0 = blockIdx.x * MLP_ROWS;

    for (int i = t; i < 64 * 128; i += 256) ws[i] = W[i];
    for (int i = t; i < MLP_ROWS * 64; i += 256) {
        const int r = i >> 6, k = i & 63;
        xs[r * 65 + k] = x[r0 * 64 + i];
    }
    __syncthreads();

    const int tx = t & 31, ty = t >> 5;
    const int c0 = tx * 4, rr = ty * 4;    // 4 rows x 4 cols per thread
    float acc[4][4];
#pragma unroll
    for (int i = 0; i < 4; ++i)
#pragma unroll
        for (int j = 0; j < 4; ++j) acc[i][j] = 0.0f;

    for (int k = 0; k < 64; ++k) {
        const float4 w4 = *(const float4*)(&ws[k * 128 + c0]);
#pragma unroll
        for (int i = 0; i < 4; ++i) {
            const float xv = xs[(rr + i) * 65 + k];
            acc[i][0] += xv * w4.x;
            acc[i][1] += xv * w4.y;
            acc[i][2] += xv * w4.z;
            acc[i][3] += xv * w4.w;
        }
    }
    const float4 b4 = *(const float4*)(&b[c0]);
#pragma unroll
    for (int i = 0; i < 4; ++i) {
        float4 o;
        o.x = fmaxf(acc[i][0] + b4.x, 0.0f);
        o.y = fmaxf(acc[i][1] + b4.y, 0.0f);
        o.z = fmaxf(acc[i][2] + b4.z, 0.0f);
        o.w = fmaxf(acc[i][3] + b4.w, 0.0f);
        *(float4*)(&h[(size_t)(r0 + rr + i) * 128 + c0]) = o;
    }
}

// --- Farthest point sampling: exact, chunk-pruned, M1-overlapped ------------
__global__ __launch_bounds__(FPS_T) void fps_kernel(
    const float* __restrict__ xs, const float* __restrict__ ys,
    const float* __restrict__ zs, const unsigned* __restrict__ orig,
    const float* __restrict__ bboxG,
    const float* __restrict__ posx, const float* __restrict__ posy,
    const float* __restrict__ posz, int* __restrict__ out_idx, int M, int N)
{
    __shared__ __align__(16) float mind[32768];   // 128 KB
    __shared__ float cmax[NC];                    // max(mind) per chunk
    __shared__ unsigned long long ckey[NC];       // (mbits<<32) | ~orig
    __shared__ unsigned alist[NC];
    __shared__ unsigned acnt[2];
    __shared__ unsigned long long mslot[2][8];    // M1 per-wave folds (dbuf)
    __shared__ unsigned long long uslot[2];       // U fold result (dbuf)

    const int t = threadIdx.x;
    const int wid = t >> 6;
    const int lane = t & 63;
    const int sg = t & 7;                          // 8-lane subgroup lane

    for (int i = t; i < 32768; i += FPS_T) mind[i] = __builtin_inff();
    cmax[t] = __builtin_inff();
    ckey[t] = 0ULL;
    if (t == 0) { acnt[0] = 0; acnt[1] = 0; uslot[0] = 0; uslot[1] = 0; out_idx[0] = 0; }
    // immutable bbox -> 6 registers per thread (chunk t)
    const float bxmn = bboxG[t * 6 + 0], bxmx = bboxG[t * 6 + 1];
    const float bymn = bboxG[t * 6 + 2], bymx = bboxG[t * 6 + 3];
    const float bzmn = bboxG[t * 6 + 4], bzmx = bboxG[t * 6 + 5];
    __syncthreads();

    float lx = posx[0], ly = posy[0], lz = posz[0];   // pick 0 = index 0

    for (int s = 1; s < M; ++s) {
        const int buf = s & 1;

        // ---- phase 1: bound test, chunk t (bbox in regs) -------------------
        bool act;
        {
            const float gx = fmaxf(fmaxf(bxmn - lx, lx - bxmx), 0.0f);
            const float gy = fmaxf(fmaxf(bymn - ly, ly - bymx), 0.0f);
            const float gz = fmaxf(fmaxf(bzmn - lz, lz - bzmx), 0.0f);
            const float dlb = (gx * gx + gy * gy + gz * gz) * 0.99999f;
            act = (dlb < cmax[t]);
            if (act)
                alist[atomicAdd(&acnt[buf], 1u)] = (unsigned)t;
        }
        __syncthreads();                                   // A
        const int na = (int)acnt[buf];

        // ---- phase 2a: 8 threads per active chunk (r11 body, verbatim) -----
        for (int r = (t >> 3); r < na; r += 64) {
            const int cc = (int)alist[r];
            unsigned long long key = 0ULL;
#pragma unroll
            for (int hh = 0; hh < 2; ++hh) {
                const int p = (cc << 6) + sg * 8 + hh * 4;      // sorted idx
                const float4 x4 = *(const float4*)&xs[p];
                const float4 y4 = *(const float4*)&ys[p];
                const float4 z4 = *(const float4*)&zs[p];
                const uint4  o4 = *(const uint4*)&orig[p];
                const int lb = (cc << 6) + ((sg * 8 + hh * 4) ^ ((cc & 15) << 2));
                float4 m4 = *(const float4*)&mind[lb];
                float dx, dy, dz, d;
                dx = x4.x - lx; dy = y4.x - ly; dz = z4.x - lz;
                d = dx * dx + dy * dy + dz * dz;
                m4.x = fminf(m4.x, d);
                { const unsigned long long k =
                      ((unsigned long long)__float_as_uint(m4.x) << 32)
                      | (unsigned)~o4.x;
                  if (k > key) key = k; }
                dx = x4.y - lx; dy = y4.y - ly; dz = z4.y - lz;
                d = dx * dx + dy * dy + dz * dz;
                m4.y = fminf(m4.y, d);
                { const unsigned long long k =
                      ((unsigned long long)__float_as_uint(m4.y) << 32)
                      | (unsigned)~o4.y;
                  if (k > key) key = k; }
                dx = x4.z - lx; dy = y4.z - ly; dz = z4.z - lz;
                d = dx * dx + dy * dy + dz * dz;
                m4.z = fminf(m4.z, d);
                { const unsigned long long k =
                      ((unsigned long long)__float_as_uint(m4.z) << 32)
                      | (unsigned)~o4.z;
                  if (k > key) key = k; }
                dx = x4.w - lx; dy = y4.w - ly; dz = z4.w - lz;
                d = dx * dx + dy * dy + dz * dz;
                m4.w = fminf(m4.w, d);
                { const unsigned long long k =
                      ((unsigned long long)__float_as_uint(m4.w) << 32)
                      | (unsigned)~o4.w;
                  if (k > key) key = k; }
                *(float4*)&mind[lb] = m4;
            }
            // reduce over the 8-lane subgroup: xor1, xor2, half-mirror
            key = dppmax64(key, 0xB1);
            key = dppmax64(key, 0x4E);
            key = dppmax64(key, 0x141);
            if (sg == 0) {
                ckey[cc] = key;
                cmax[cc] = __uint_as_float((unsigned)(key >> 32));
            }
        }

        // ---- phase 2b: M1 fold over INACTIVE chunks (stable ckey) ----------
        // Runs in the same interval; mostly hidden under phase 2a's latency
        // (only na*8 <= 64 threads are busy there in steady state).
        {
            unsigned long long mk = act ? 0ULL : ckey[t];
            mk = dppmax64(mk, 0xB1);
            mk = dppmax64(mk, 0x4E);
            mk = dppmax64(mk, 0x141);
            mk = dppmax64(mk, 0x140);
            mk = dppmax64(mk, 0x142);
            mk = dppmax64(mk, 0x143);
            if (lane == 63) mslot[buf][wid] = mk;
        }
        __syncthreads();                                   // B

        // ---- phase 3: U fold over updated chunks, wave 0 only --------------
        if (wid == 0) {
            unsigned long long uk = 0ULL;
            for (int r = lane; r < na; r += 64) {
                const unsigned long long k = ckey[alist[r]];
                if (k > uk) uk = k;
            }
            uk = dppmax64(uk, 0xB1);
            uk = dppmax64(uk, 0x4E);
            uk = dppmax64(uk, 0x141);
            uk = dppmax64(uk, 0x140);
            uk = dppmax64(uk, 0x142);
            uk = dppmax64(uk, 0x143);
            if (lane == 63) uslot[buf] = uk;
        }
        if (t == 0) acnt[buf] = 0;                         // reuse at s+2
        __syncthreads();                                   // C

        // ---- pick = max(U, M1 slots); coords from global (hidden loads) ----
        unsigned long long wk = uslot[buf];
#pragma unroll
        for (int w = 0; w < 8; ++w) {
            const unsigned long long o = mslot[buf][w];
            if (o > wk) wk = o;
        }
        const unsigned og = ~(unsigned)wk;                 // original index
        if (t == 0) out_idx[s] = (int)og;
        lx = posx[og]; ly = posy[og]; lz = posz[og];       // immutable global
        // mslot/uslot/acnt[buf] next rewritten at s+2, >=2 barriers later.
    }
}

// --- KNN (exact top-16 by (d, idx)) + gather-max over h + sub outputs -------
__global__ __launch_bounds__(256) void knn_kernel(
    const float* __restrict__ posx, const float* __restrict__ posy,
    const float* __restrict__ posz, const int* __restrict__ idx,
    const float* __restrict__ h, const float* __restrict__ pos,
    const int* __restrict__ batch, float* __restrict__ out,
    float* __restrict__ out_subpos, int* __restrict__ out_subbatch,
    int N, int M, int Cout)
{
    const int q = (int)((blockIdx.x * (unsigned)blockDim.x + threadIdx.x) >> 6);
    const int lane = threadIdx.x & 63;
    if (q >= M) return;

    const int qi = idx[q];
    const float qx = posx[qi], qy = posy[qi], qz = posz[qi];

    // per-lane top-16 (replace-max), wave-shared rejection threshold T
    float d16[KNN_K]; int i16[KNN_K];
#pragma unroll
    for (int k = 0; k < KNN_K; ++k) { d16[k] = __builtin_inff(); i16[k] = 0x7fffffff; }
    float lmax = __builtin_inff();
    int lslot = 0;
    float T = __builtin_inff();

    const int iters = N >> 6;
    for (int c = 0; c < iters; ++c) {
        const int p = c * 64 + lane;
        const float dx = posx[p] - qx;
        const float dy = posy[p] - qy;
        const float dz = posz[p] - qz;
        const float d = dx * dx + dy * dy + dz * dz;
        if (d < T && d < lmax) {
            d16[lslot] = d; i16[lslot] = p;
            lmax = d16[0]; lslot = 0;
#pragma unroll
            for (int k = 1; k < KNN_K; ++k)
                if (d16[k] > lmax) { lmax = d16[k]; lslot = k; }
        }
        if ((c & 31) == 31) {
            float tt = lmax;
#pragma unroll
            for (int off = 32; off > 0; off >>= 1)
                tt = fminf(tt, __shfl_xor(tt, off));
            T = tt;   // global-16th-so-far <= min over lanes of lane-16th: exact reject
        }
    }

    // merge: 16 rounds of wave extract-min with (d, idx) lexicographic order
    int nbr[KNN_K];
#pragma unroll
    for (int r = 0; r < KNN_K; ++r) {
        float lv = d16[0]; int ls = 0;
#pragma unroll
        for (int k = 1; k < KNN_K; ++k)
            if (d16[k] < lv || (d16[k] == lv && i16[k] < i16[ls])) { lv = d16[k]; ls = k; }
        float mv = lv; int mi = i16[ls];
#pragma unroll
        for (int off = 32; off > 0; off >>= 1) {
            const float ov = __shfl_xor(mv, off);
            const int   oi = __shfl_xor(mi, off);
            if (ov < mv || (ov == mv && oi < mi)) { mv = ov; mi = oi; }
        }
        if (i16[ls] == mi) d16[ls] = __builtin_inff();   // unique owner removes it
        nbr[r] = mi;
    }

    // out[q] = max over 16 neighbors of h rows (coalesced per-row loads)
    for (int c = lane; c < Cout; c += 64) {
        float a = -__builtin_inff();
#pragma unroll
        for (int r = 0; r < KNN_K; ++r)
            a = fmaxf(a, h[(size_t)nbr[r] * Cout + c]);
        out[(size_t)q * Cout + c] = a;
    }
    if (lane < 3) out_subpos[q * 3 + lane] = pos[qi * 3 + lane];
    if (lane == 3) out_subbatch[q] = batch[qi];
}

// ---------------------------------------------------------------------------
extern "C" void kernel_launch(void* const* d_in, const int* in_sizes, int n_in,
                              void* d_out, int out_size, void* d_ws, size_t ws_size,
                              hipStream_t stream)
{
    const float* x     = (const float*)d_in[0];
    const float* pos   = (const float*)d_in[1];
    const int*   batch = (const int*)d_in[2];
    const float* W     = (const float*)d_in[3];
    const float* b     = (const float*)d_in[4];

    const int N    = in_sizes[2];       // 32768 (batch has one entry per point)
    const int Cout = in_sizes[4];       // 128
    const int M    = N / 4;             // RATIO = 0.25 -> 8192

    // workspace layout (floats): posx | posy | posz | idx(int) | h[N*Cout]
    float* posx = (float*)d_ws;
    float* posy = posx + N;
    float* posz = posy + N;
    int*   idx  = (int*)(posz + N);
    float* h    = (float*)(idx + M);

    // sort/bbox scratch ALIASES the h region (fps finishes before mlp writes
    // h; single stream serializes): xs|ys|zs|orig|bboxG = 4N + 3072 floats.
    float*    xs    = h;
    float*    ys    = xs + N;
    float*    zs    = ys + N;
    unsigned* orig  = (unsigned*)(zs + N);
    float*    bboxG = (float*)(orig + N);

    float* out          = (float*)d_out;
    float* out_subpos   = out + (size_t)M * Cout;
    int*   out_subbatch = (int*)(out_subpos + (size_t)M * 3);

    prep_kernel<<<(N + 255) / 256, 256, 0, stream>>>(pos, posx, posy, posz, N);
    sort_kernel<<<1, 1024, 0, stream>>>(posx, posy, posz, xs, ys, zs, orig, N);
    bbox_kernel<<<NC, 64, 0, stream>>>(xs, ys, zs, bboxG);
    fps_kernel<<<1, FPS_T, 0, stream>>>(xs, ys, zs, orig, bboxG,
                                        posx, posy, posz, idx, M, N);
    mlp_kernel<<<N / MLP_ROWS, 256, 0, stream>>>(x, W, b, h, N);
    knn_kernel<<<(M * 64) / 256, 256, 0, stream>>>(posx, posy, posz, idx, h, pos, batch,
                                                   out, out_subpos, out_subbatch, N, M, Cout);
}

// Round 12
// 12267.274 us; speedup vs baseline: 1.1305x; 1.1305x over previous
//
#include <hip/hip_runtime.h>

// ---------------------------------------------------------------------------
// TransitionDown: FPS (M=N/4) -> KNN(K=16) -> Linear(64->128)+ReLU -> max-pool
// Round 16: REVERT to r11 — the measured-best structure (12.29 ms total,
// fps 1.43us/step). Seven structural variants bracket the floor:
//   r9 2.62 | r10 4.79 | r11 1.43 | r12 4.64 | r13 1.61 | r14 1.53 | r15 1.61
// Every deviation (fewer barriers, 1-wave, payload-carry, fold-split) lost.
// The step floor = 3 wave-coordination points + LDS round-trips on one CU;
// 8191 serial steps x 1.43us ~= 11.7ms + 0.6ms aux kernels ~= 12.3ms total.
// Exact chunk-pruned FPS (bit-exact vs brute force):
//   - Morton counting sort -> 512 chunks of 64 pts, tight bboxes.
//   - skip chunk iff d_lb(pick,bbox)*0.99999 >= chunkmax (slack covers all
//     fp rounding: fminf would be identity => skip cannot change any mind).
//   - dynamic alist distribution, 8 threads/active chunk, in-lane u64 key
//     fold + 3-level DPP subgroup reduce; phase-3 6-level DPP u64 tree.
//   - key (mbits<<32)|~orig: u64 max == (max value, then lowest original
//     index) == jnp.argmax tie semantics.
// ---------------------------------------------------------------------------

#define FPS_T   512
#define NC      512
#define KNN_K   16
#define MLP_ROWS 32

#define DPPU(X, CTRL) ((unsigned)__builtin_amdgcn_update_dpp(                 \
    (int)(X), (int)(X), (CTRL), 0xf, 0xf, false))

// 64-bit max-combine with DPP-shifted partner (old=src: inactive partner
// lanes yield own value -> no-op combine; validated pattern r8-r15).
__device__ __forceinline__ unsigned long long dppmax64(unsigned long long k,
                                                       const int ctrl)
{
    const unsigned lo = (unsigned)k, hi = (unsigned)(k >> 32);
    unsigned nlo, nhi;
    switch (ctrl) {   // ctrl must be a literal constant per call site
    case 0xB1:  nlo = DPPU(lo, 0xB1);  nhi = DPPU(hi, 0xB1);  break;
    case 0x4E:  nlo = DPPU(lo, 0x4E);  nhi = DPPU(hi, 0x4E);  break;
    case 0x141: nlo = DPPU(lo, 0x141); nhi = DPPU(hi, 0x141); break;
    case 0x140: nlo = DPPU(lo, 0x140); nhi = DPPU(hi, 0x140); break;
    case 0x142: nlo = DPPU(lo, 0x142); nhi = DPPU(hi, 0x142); break;
    default:    nlo = DPPU(lo, 0x143); nhi = DPPU(hi, 0x143); break;
    }
    const unsigned long long nk = ((unsigned long long)nhi << 32) | nlo;
    return nk > k ? nk : k;
}

// --- SoA transpose of pos for coalesced per-coordinate access ---------------
__global__ void prep_kernel(const float* __restrict__ pos, float* __restrict__ posx,
                            float* __restrict__ posy, float* __restrict__ posz, int N)
{
    const int i = blockIdx.x * blockDim.x + threadIdx.x;
    if (i < N) {
        posx[i] = pos[3 * i + 0];
        posy[i] = pos[3 * i + 1];
        posz[i] = pos[3 * i + 2];
    }
}

// --- Morton-bucket counting sort (spatial permutation; orig idx carried) ----
__device__ __forceinline__ unsigned spread4(unsigned x)
{
    return (x & 1u) | ((x & 2u) << 2) | ((x & 4u) << 4) | ((x & 8u) << 6);
}
__device__ __forceinline__ unsigned mcode(float x, float y, float z)
{
    int qx = (int)((x + 6.0f) * (16.0f / 12.0f));
    int qy = (int)((y + 6.0f) * (16.0f / 12.0f));
    int qz = (int)((z + 6.0f) * (16.0f / 12.0f));
    qx = qx < 0 ? 0 : (qx > 15 ? 15 : qx);
    qy = qy < 0 ? 0 : (qy > 15 ? 15 : qy);
    qz = qz < 0 ? 0 : (qz > 15 ? 15 : qz);
    return spread4((unsigned)qx) | (spread4((unsigned)qy) << 1)
         | (spread4((unsigned)qz) << 2);
}

__global__ __launch_bounds__(1024) void sort_kernel(
    const float* __restrict__ posx, const float* __restrict__ posy,
    const float* __restrict__ posz, float* __restrict__ xs,
    float* __restrict__ ys, float* __restrict__ zs,
    unsigned* __restrict__ orig, int N)
{
    __shared__ unsigned cnt[4096];
    __shared__ unsigned base[4096];
    const int t = threadIdx.x;

    for (int i = t; i < 4096; i += 1024) cnt[i] = 0;
    __syncthreads();
    for (int i = t; i < N; i += 1024)
        atomicAdd(&cnt[mcode(posx[i], posy[i], posz[i])], 1u);
    __syncthreads();
    if (t == 0) {
        unsigned run = 0;
        for (int c = 0; c < 4096; ++c) { base[c] = run; run += cnt[c]; }
    }
    __syncthreads();
    for (int i = t; i < 4096; i += 1024) cnt[i] = 0;
    __syncthreads();
    for (int i = t; i < N; i += 1024) {
        const float px = posx[i], py = posy[i], pz = posz[i];
        const unsigned m = mcode(px, py, pz);
        const unsigned d = base[m] + atomicAdd(&cnt[m], 1u);
        xs[d] = px; ys[d] = py; zs[d] = pz; orig[d] = (unsigned)i;
    }
}

// --- per-chunk bbox (exact fmin/fmax of member coords) ----------------------
__global__ __launch_bounds__(64) void bbox_kernel(
    const float* __restrict__ xs, const float* __restrict__ ys,
    const float* __restrict__ zs, float* __restrict__ bboxG)
{
    const int c = blockIdx.x, l = threadIdx.x;
    const int i = c * 64 + l;
    float xmn = xs[i], xmx = xmn;
    float ymn = ys[i], ymx = ymn;
    float zmn = zs[i], zmx = zmn;
#pragma unroll
    for (int off = 32; off > 0; off >>= 1) {
        xmn = fminf(xmn, __shfl_xor(xmn, off));
        xmx = fmaxf(xmx, __shfl_xor(xmx, off));
        ymn = fminf(ymn, __shfl_xor(ymn, off));
        ymx = fmaxf(ymx, __shfl_xor(ymx, off));
        zmn = fminf(zmn, __shfl_xor(zmn, off));
        zmx = fmaxf(zmx, __shfl_xor(zmx, off));
    }
    if (l == 0) {
        float* o = &bboxG[c * 6];
        o[0] = xmn; o[1] = xmx; o[2] = ymn; o[3] = ymx; o[4] = zmn; o[5] = zmx;
    }
}

// --- h = relu(x @ W + b), x[N,64], W[64,128], h[N,128] ----------------------
__global__ __launch_bounds__(256) void mlp_kernel(
    const float* __restrict__ x, const float* __restrict__ W,
    const float* __restrict__ b, float* __restrict__ h, int N)
{
    __shared__ float ws[64 * 128];
    __shared__ float xs[MLP_ROWS * 65];   // +1 pad: breaks 8-way bank conflict
    const int t = threadIdx.x;
    const int r0 = blockIdx.x * MLP_ROWS;

    for (int i = t; i < 64 * 128; i += 256) ws[i] = W[i];
    for (int i = t; i < MLP_ROWS * 64; i += 256) {
        const int r = i >> 6, k = i & 63;
        xs[r * 65 + k] = x[r0 * 64 + i];
    }
    __syncthreads();

    const int tx = t & 31, ty = t >> 5;
    const int c0 = tx * 4, rr = ty * 4;    // 4 rows x 4 cols per thread
    float acc[4][4];
#pragma unroll
    for (int i = 0; i < 4; ++i)
#pragma unroll
        for (int j = 0; j < 4; ++j) acc[i][j] = 0.0f;

    for (int k = 0; k < 64; ++k) {
        const float4 w4 = *(const float4*)(&ws[k * 128 + c0]);
#pragma unroll
        for (int i = 0; i < 4; ++i) {
            const float xv = xs[(rr + i) * 65 + k];
            acc[i][0] += xv * w4.x;
            acc[i][1] += xv * w4.y;
            acc[i][2] += xv * w4.z;
            acc[i][3] += xv * w4.w;
        }
    }
    const float4 b4 = *(const float4*)(&b[c0]);
#pragma unroll
    for (int i = 0; i < 4; ++i) {
        float4 o;
        o.x = fmaxf(acc[i][0] + b4.x, 0.0f);
        o.y = fmaxf(acc[i][1] + b4.y, 0.0f);
        o.z = fmaxf(acc[i][2] + b4.z, 0.0f);
        o.w = fmaxf(acc[i][3] + b4.w, 0.0f);
        *(float4*)(&h[(size_t)(r0 + rr + i) * 128 + c0]) = o;
    }
}

// --- Farthest point sampling: exact, chunk-pruned ---------------------------
// pick = argmax over exact mind; ties -> lowest ORIGINAL index.
// mind LDS layout: chunk c, point i at word c*64 + (i ^ ((c&15)<<2))
// (XOR of bits 2..5: bijective per chunk, preserves float4 contiguity,
// spreads banks across active chunks).
__global__ __launch_bounds__(FPS_T) void fps_kernel(
    const float* __restrict__ xs, const float* __restrict__ ys,
    const float* __restrict__ zs, const unsigned* __restrict__ orig,
    const float* __restrict__ bboxG,
    const float* __restrict__ posx, const float* __restrict__ posy,
    const float* __restrict__ posz, int* __restrict__ out_idx, int M, int N)
{
    __shared__ __align__(16) float mind[32768];   // 128 KB
    __shared__ float cmax[NC];                    // max(mind) per chunk
    __shared__ unsigned long long ckey[NC];       // (mbits<<32) | ~orig
    __shared__ unsigned alist[NC];
    __shared__ unsigned acnt[2];
    __shared__ unsigned long long wslot[2][8];

    const int t = threadIdx.x;
    const int wid = t >> 6;
    const int lane = t & 63;
    const int sg = t & 7;                          // 8-lane subgroup lane

    for (int i = t; i < 32768; i += FPS_T) mind[i] = __builtin_inff();
    cmax[t] = __builtin_inff();
    ckey[t] = 0ULL;
    if (t == 0) { acnt[0] = 0; acnt[1] = 0; out_idx[0] = 0; }
    // immutable bbox -> 6 registers per thread (chunk t)
    const float bxmn = bboxG[t * 6 + 0], bxmx = bboxG[t * 6 + 1];
    const float bymn = bboxG[t * 6 + 2], bymx = bboxG[t * 6 + 3];
    const float bzmn = bboxG[t * 6 + 4], bzmx = bboxG[t * 6 + 5];
    __syncthreads();

    float lx = posx[0], ly = posy[0], lz = posz[0];   // pick 0 = index 0

    for (int s = 1; s < M; ++s) {
        const int buf = s & 1;

        // ---- phase 1: bound test, chunk t (bbox in regs) -------------------
        {
            const float gx = fmaxf(fmaxf(bxmn - lx, lx - bxmx), 0.0f);
            const float gy = fmaxf(fmaxf(bymn - ly, ly - bymx), 0.0f);
            const float gz = fmaxf(fmaxf(bzmn - lz, lz - bzmx), 0.0f);
            const float dlb = (gx * gx + gy * gy + gz * gz) * 0.99999f;
            if (dlb < cmax[t])
                alist[atomicAdd(&acnt[buf], 1u)] = (unsigned)t;
        }
        __syncthreads();                                   // A
        const int na = (int)acnt[buf];

        // ---- phase 2: 8 threads per active chunk, in-lane u64 keys ---------
        for (int r = (t >> 3); r < na; r += 64) {
            const int cc = (int)alist[r];
            unsigned long long key = 0ULL;
#pragma unroll
            for (int hh = 0; hh < 2; ++hh) {
                const int p = (cc << 6) + sg * 8 + hh * 4;      // sorted idx
                const float4 x4 = *(const float4*)&xs[p];
                const float4 y4 = *(const float4*)&ys[p];
                const float4 z4 = *(const float4*)&zs[p];
                const uint4  o4 = *(const uint4*)&orig[p];
                const int lb = (cc << 6) + ((sg * 8 + hh * 4) ^ ((cc & 15) << 2));
                float4 m4 = *(const float4*)&mind[lb];
                float dx, dy, dz, d;
                dx = x4.x - lx; dy = y4.x - ly; dz = z4.x - lz;
                d = dx * dx + dy * dy + dz * dz;
                m4.x = fminf(m4.x, d);
                { const unsigned long long k =
                      ((unsigned long long)__float_as_uint(m4.x) << 32)
                      | (unsigned)~o4.x;
                  if (k > key) key = k; }
                dx = x4.y - lx; dy = y4.y - ly; dz = z4.y - lz;
                d = dx * dx + dy * dy + dz * dz;
                m4.y = fminf(m4.y, d);
                { const unsigned long long k =
                      ((unsigned long long)__float_as_uint(m4.y) << 32)
                      | (unsigned)~o4.y;
                  if (k > key) key = k; }
                dx = x4.z - lx; dy = y4.z - ly; dz = z4.z - lz;
                d = dx * dx + dy * dy + dz * dz;
                m4.z = fminf(m4.z, d);
                { const unsigned long long k =
                      ((unsigned long long)__float_as_uint(m4.z) << 32)
                      | (unsigned)~o4.z;
                  if (k > key) key = k; }
                dx = x4.w - lx; dy = y4.w - ly; dz = z4.w - lz;
                d = dx * dx + dy * dy + dz * dz;
                m4.w = fminf(m4.w, d);
                { const unsigned long long k =
                      ((unsigned long long)__float_as_uint(m4.w) << 32)
                      | (unsigned)~o4.w;
                  if (k > key) key = k; }
                *(float4*)&mind[lb] = m4;
            }
            // reduce over the 8-lane subgroup (uniform r per group -> no
            // partial-group divergence): xor1, xor2, half-mirror
            key = dppmax64(key, 0xB1);
            key = dppmax64(key, 0x4E);
            key = dppmax64(key, 0x141);
            if (sg == 0) {
                ckey[cc] = key;
                cmax[cc] = __uint_as_float((unsigned)(key >> 32));
            }
        }
        __syncthreads();                                   // B

        // ---- phase 3: global argmax over 512 chunk keys --------------------
        {
            unsigned long long k3 = ckey[t];
            k3 = dppmax64(k3, 0xB1);
            k3 = dppmax64(k3, 0x4E);
            k3 = dppmax64(k3, 0x141);
            k3 = dppmax64(k3, 0x140);
            k3 = dppmax64(k3, 0x142);
            k3 = dppmax64(k3, 0x143);
            if (lane == 63) wslot[buf][wid] = k3;          // lane 63 holds max
        }
        if (t == 0) acnt[buf] = 0;                         // reuse at s+2
        __syncthreads();                                   // C
        unsigned long long wk = wslot[buf][0];
#pragma unroll
        for (int w = 1; w < FPS_T / 64; ++w) {
            const unsigned long long o = wslot[buf][w];
            if (o > wk) wk = o;
        }
        const unsigned og = ~(unsigned)wk;                 // original index
        if (t == 0) out_idx[s] = (int)og;
        lx = posx[og]; ly = posy[og]; lz = posz[og];       // immutable global
        // wslot/acnt[buf] next rewritten at s+2, >=2 barriers later.
    }
}

// --- KNN (exact top-16 by (d, idx)) + gather-max over h + sub outputs -------
__global__ __launch_bounds__(256) void knn_kernel(
    const float* __restrict__ posx, const float* __restrict__ posy,
    const float* __restrict__ posz, const int* __restrict__ idx,
    const float* __restrict__ h, const float* __restrict__ pos,
    const int* __restrict__ batch, float* __restrict__ out,
    float* __restrict__ out_subpos, int* __restrict__ out_subbatch,
    int N, int M, int Cout)
{
    const int q = (int)((blockIdx.x * (unsigned)blockDim.x + threadIdx.x) >> 6);
    const int lane = threadIdx.x & 63;
    if (q >= M) return;

    const int qi = idx[q];
    const float qx = posx[qi], qy = posy[qi], qz = posz[qi];

    // per-lane top-16 (replace-max), wave-shared rejection threshold T
    float d16[KNN_K]; int i16[KNN_K];
#pragma unroll
    for (int k = 0; k < KNN_K; ++k) { d16[k] = __builtin_inff(); i16[k] = 0x7fffffff; }
    float lmax = __builtin_inff();
    int lslot = 0;
    float T = __builtin_inff();

    const int iters = N >> 6;
    for (int c = 0; c < iters; ++c) {
        const int p = c * 64 + lane;
        const float dx = posx[p] - qx;
        const float dy = posy[p] - qy;
        const float dz = posz[p] - qz;
        const float d = dx * dx + dy * dy + dz * dz;
        if (d < T && d < lmax) {
            d16[lslot] = d; i16[lslot] = p;
            lmax = d16[0]; lslot = 0;
#pragma unroll
            for (int k = 1; k < KNN_K; ++k)
                if (d16[k] > lmax) { lmax = d16[k]; lslot = k; }
        }
        if ((c & 31) == 31) {
            float tt = lmax;
#pragma unroll
            for (int off = 32; off > 0; off >>= 1)
                tt = fminf(tt, __shfl_xor(tt, off));
            T = tt;   // global-16th-so-far <= min over lanes of lane-16th: exact reject
        }
    }

    // merge: 16 rounds of wave extract-min with (d, idx) lexicographic order
    int nbr[KNN_K];
#pragma unroll
    for (int r = 0; r < KNN_K; ++r) {
        float lv = d16[0]; int ls = 0;
#pragma unroll
        for (int k = 1; k < KNN_K; ++k)
            if (d16[k] < lv || (d16[k] == lv && i16[k] < i16[ls])) { lv = d16[k]; ls = k; }
        float mv = lv; int mi = i16[ls];
#pragma unroll
        for (int off = 32; off > 0; off >>= 1) {
            const float ov = __shfl_xor(mv, off);
            const int   oi = __shfl_xor(mi, off);
            if (ov < mv || (ov == mv && oi < mi)) { mv = ov; mi = oi; }
        }
        if (i16[ls] == mi) d16[ls] = __builtin_inff();   // unique owner removes it
        nbr[r] = mi;
    }

    // out[q] = max over 16 neighbors of h rows (coalesced per-row loads)
    for (int c = lane; c < Cout; c += 64) {
        float a = -__builtin_inff();
#pragma unroll
        for (int r = 0; r < KNN_K; ++r)
            a = fmaxf(a, h[(size_t)nbr[r] * Cout + c]);
        out[(size_t)q * Cout + c] = a;
    }
    if (lane < 3) out_subpos[q * 3 + lane] = pos[qi * 3 + lane];
    if (lane == 3) out_subbatch[q] = batch[qi];
}

// ---------------------------------------------------------------------------
extern "C" void kernel_launch(void* const* d_in, const int* in_sizes, int n_in,
                              void* d_out, int out_size, void* d_ws, size_t ws_size,
                              hipStream_t stream)
{
    const float* x     = (const float*)d_in[0];
    const float* pos   = (const float*)d_in[1];
    const int*   batch = (const int*)d_in[2];
    const float* W     = (const float*)d_in[3];
    const float* b     = (const float*)d_in[4];

    const int N    = in_sizes[2];       // 32768 (batch has one entry per point)
    const int Cout = in_sizes[4];       // 128
    const int M    = N / 4;             // RATIO = 0.25 -> 8192

    // workspace layout (floats): posx | posy | posz | idx(int) | h[N*Cout]
    float* posx = (float*)d_ws;
    float* posy = posx + N;
    float* posz = posy + N;
    int*   idx  = (int*)(posz + N);
    float* h    = (float*)(idx + M);

    // sort/bbox scratch ALIASES the h region (fps finishes before mlp writes
    // h; single stream serializes): xs|ys|zs|orig|bboxG = 4N + 3072 floats.
    float*    xs    = h;
    float*    ys    = xs + N;
    float*    zs    = ys + N;
    unsigned* orig  = (unsigned*)(zs + N);
    float*    bboxG = (float*)(orig + N);

    float* out          = (float*)d_out;
    float* out_subpos   = out + (size_t)M * Cout;
    int*   out_subbatch = (int*)(out_subpos + (size_t)M * 3);

    prep_kernel<<<(N + 255) / 256, 256, 0, stream>>>(pos, posx, posy, posz, N);
    sort_kernel<<<1, 1024, 0, stream>>>(posx, posy, posz, xs, ys, zs, orig, N);
    bbox_kernel<<<NC, 64, 0, stream>>>(xs, ys, zs, bboxG);
    fps_kernel<<<1, FPS_T, 0, stream>>>(xs, ys, zs, orig, bboxG,
                                        posx, posy, posz, idx, M, N);
    mlp_kernel<<<N / MLP_ROWS, 256, 0, stream>>>(x, W, b, h, N);
    knn_kernel<<<(M * 64) / 256, 256, 0, stream>>>(posx, posy, posz, idx, h, pos, batch,
                                                   out, out_subpos, out_subbatch, N, M, Cout);
}